// Round 10
// baseline (137.856 us; speedup 1.0000x reference)
//
#include <hip/hip_runtime.h>
#include <hip/hip_bf16.h>
#include <stdint.h>
#include <math.h>

// Problem dims
#define B_    1024
#define LAT   64
#define FCON  256
#define IN_SZ 320          // LAT + FCON
#define HID   512
#define E_    8
#define GH    64
#define INTER 576          // LAT + HID
#define OUT_SZ 512
#define NTOT  4096         // E_ * 512
#define KI0   10           // IN_SZ/32
#define KI12  18           // INTER/32

typedef __attribute__((ext_vector_type(8))) __bf16 bf16x8;
typedef __attribute__((ext_vector_type(4))) float  f32x4;

__device__ __forceinline__ float elu_f(float x) { return x > 0.f ? x : expf(x) - 1.f; }
__device__ __forceinline__ __bf16 to_bf16(float f) {
    __hip_bfloat16 h = __float2bfloat16(f);
    return *reinterpret_cast<__bf16*>(&h);
}

// async 16B global -> LDS (dest = wave-uniform base + lane*16)
__device__ __forceinline__ void async_ld16(const void* g, void* l) {
    __builtin_amdgcn_global_load_lds(
        (const __attribute__((address_space(1))) unsigned int*)g,
        (__attribute__((address_space(3))) unsigned int*)l,
        16, 0, 0);
}

// ---------------------------------------------------------------------------
// Fragment layout (mfma_f32_16x16x32_bf16 A/B operand, m89-verified):
//   frag(t0,k0)[lane][j] = X[t0 + (lane&15)][k0 + (lane>>4)*8 + j],  j=0..7
// Packed storage: buf[(tile_idx*KI + ki)*64 + lane] : bf16x8 (16 B/lane).
// ---------------------------------------------------------------------------

#define SMEM_PREP 32768                      // D1 scratch (gate 24.5K / wpack 17K)
#define WPAD2 133                            // 32 x 133 floats (<=2-way banks)

// ----- zc pack (R3-verified, 16-wide frags) --------------------------------
__device__ __forceinline__ void do_zcpack(
    int bx, const float* __restrict__ z, const float* __restrict__ c,
    bf16x8* __restrict__ Ap0, bf16x8* __restrict__ Ap1, bf16x8* __restrict__ Ap2)
{
    const int wid  = bx * 4 + (threadIdx.x >> 6);
    const int lane = threadIdx.x & 63, q = lane >> 4, r = lane & 15;
    bf16x8 v;
    if (wid < 128) {                       // z fragment: mi in [0,64), ki in {0,1}
        const int mi = wid >> 1, ki = wid & 1;
        const float* src = z + (size_t)(mi * 16 + r) * LAT + ki * 32 + q * 8;
        const f32x4 lo = *(const f32x4*)src, hi = *(const f32x4*)(src + 4);
#pragma unroll
        for (int j = 0; j < 4; j++) { v[j] = to_bf16(lo[j]); v[j + 4] = to_bf16(hi[j]); }
        Ap0[((size_t)mi * KI0  + ki) * 64 + lane] = v;
        Ap1[((size_t)mi * KI12 + ki) * 64 + lane] = v;
        Ap2[((size_t)mi * KI12 + ki) * 64 + lane] = v;
    } else {                               // c fragment: ki in [2,10)
        const int cid = wid - 128;
        const int mi = cid >> 3, ki = 2 + (cid & 7);
        const float* src = c + (size_t)(mi * 16 + r) * FCON + (ki - 2) * 32 + q * 8;
        const f32x4 lo = *(const f32x4*)src, hi = *(const f32x4*)(src + 4);
#pragma unroll
        for (int j = 0; j < 4; j++) { v[j] = to_bf16(lo[j]); v[j + 4] = to_bf16(hi[j]); }
        Ap0[((size_t)mi * KI0 + ki) * 64 + lane] = v;
    }
}

// ----- weight pack, 128-col half-tiles (17 KB LDS) -------------------------
__device__ __forceinline__ void do_wpackh(
    int f, const float* __restrict__ w, bf16x8* __restrict__ Wp, int KI,
    float* __restrict__ lds)
{
    const int e = f / (KI * 4), rem = f % (KI * 4);
    const int ki = rem >> 2, oq = rem & 3;
    const int K = KI * 32;
    const float* base = w + ((size_t)e * K + ki * 32) * 512 + oq * 128;

#pragma unroll
    for (int p = 0; p < 4; ++p) {
        const int idx = p * 256 + threadIdx.x;   // 0..1023
        const int kl = idx >> 5, c4 = idx & 31;  // k-row 0..31, float4 col 0..31
        const f32x4 v = *(const f32x4*)(base + (size_t)kl * 512 + c4 * 4);
        float* d = lds + kl * WPAD2 + c4 * 4;
        d[0] = v[0]; d[1] = v[1]; d[2] = v[2]; d[3] = v[3];
    }
    __syncthreads();

    const int wv = threadIdx.x >> 6, lane = threadIdx.x & 63;
    const int q = lane >> 4, r = lane & 15;
#pragma unroll
    for (int ff = 0; ff < 2; ++ff) {
        const int fo = wv * 2 + ff;              // 0..7 local o-tile
        const int ol = fo * 16 + r;
        bf16x8 v;
#pragma unroll
        for (int j = 0; j < 8; ++j) v[j] = to_bf16(lds[(q * 8 + j) * WPAD2 + ol]);
        const int ni = e * 32 + oq * 8 + fo;
        Wp[((size_t)ni * KI + ki) * 64 + lane] = v;
    }
}

// ----- gate (R3-verified) --------------------------------------------------
__device__ __forceinline__ void do_gate(
    int bx, const float* __restrict__ z, const float* __restrict__ c,
    const float* __restrict__ gw1, const float* __restrict__ gb1,
    const float* __restrict__ gw2, const float* __restrict__ gb2,
    const float* __restrict__ gw3, const float* __restrict__ gb3,
    float* __restrict__ coeff, float* __restrict__ smem)
{
    float* xs = smem;                 // [16][320]
    float* h  = smem + 16 * 320;      // [16][64], wave-private rows
    const int r0 = bx * 16;
    const int wave = threadIdx.x >> 6, lane = threadIdx.x & 63;

#pragma unroll
    for (int p = 0; p < 5; ++p) {
        const int idx = p * 256 + threadIdx.x;     // 0..1279
        const int row = idx / 80, c4 = idx % 80;   // 80 float4 per row
        const float* src = (c4 < 16)
            ? (z + (size_t)(r0 + row) * LAT  + c4 * 4)
            : (c + (size_t)(r0 + row) * FCON + (c4 - 16) * 4);
        *(f32x4*)(xs + row * 320 + c4 * 4) = *(const f32x4*)src;
    }
    __syncthreads();

    float a0, a1, a2, a3;
    {
        const float b = gb1[lane];
        a0 = b; a1 = b; a2 = b; a3 = b;
        const float* x0 = xs + (wave * 4 + 0) * 320;
        const float* x1 = xs + (wave * 4 + 1) * 320;
        const float* x2 = xs + (wave * 4 + 2) * 320;
        const float* x3 = xs + (wave * 4 + 3) * 320;
#pragma unroll 8
        for (int i = 0; i < IN_SZ; ++i) {
            const float wv = gw1[i * GH + lane];
            a0 = fmaf(x0[i], wv, a0);
            a1 = fmaf(x1[i], wv, a1);
            a2 = fmaf(x2[i], wv, a2);
            a3 = fmaf(x3[i], wv, a3);
        }
        h[(wave * 4 + 0) * GH + lane] = elu_f(a0);
        h[(wave * 4 + 1) * GH + lane] = elu_f(a1);
        h[(wave * 4 + 2) * GH + lane] = elu_f(a2);
        h[(wave * 4 + 3) * GH + lane] = elu_f(a3);
    }
    {
        const float b = gb2[lane];
        a0 = b; a1 = b; a2 = b; a3 = b;
        const float* h0 = h + (wave * 4 + 0) * GH;
        const float* h1 = h + (wave * 4 + 1) * GH;
        const float* h2 = h + (wave * 4 + 2) * GH;
        const float* h3 = h + (wave * 4 + 3) * GH;
#pragma unroll 8
        for (int i = 0; i < GH; ++i) {
            const float wv = gw2[i * GH + lane];
            a0 = fmaf(h0[i], wv, a0);
            a1 = fmaf(h1[i], wv, a1);
            a2 = fmaf(h2[i], wv, a2);
            a3 = fmaf(h3[i], wv, a3);
        }
        h[(wave * 4 + 0) * GH + lane] = elu_f(a0);
        h[(wave * 4 + 1) * GH + lane] = elu_f(a1);
        h[(wave * 4 + 2) * GH + lane] = elu_f(a2);
        h[(wave * 4 + 3) * GH + lane] = elu_f(a3);
    }
    if (lane < 32) {
        const int rloc = lane >> 3, e = lane & 7;
        const float* hr = h + (wave * 4 + rloc) * GH;
        float lg = gb3[e];
#pragma unroll 8
        for (int i = 0; i < GH; ++i) lg = fmaf(hr[i], gw3[i * E_ + e], lg);
        float mx = lg;
        mx = fmaxf(mx, __shfl_xor(mx, 1, 8));
        mx = fmaxf(mx, __shfl_xor(mx, 2, 8));
        mx = fmaxf(mx, __shfl_xor(mx, 4, 8));
        const float ex = expf(lg - mx);
        float sm = ex;
        sm += __shfl_xor(sm, 1, 8);
        sm += __shfl_xor(sm, 2, 8);
        sm += __shfl_xor(sm, 4, 8);
        coeff[(size_t)(r0 + wave * 4 + rloc) * E_ + e] = ex / sm;
    }
}

// ---------------------------------------------------------------------------
// Layer body v9: DEPTH-3 pipeline, 4 LDS buffers (64 KB), ONE barrier/chunk.
// Per chunk per wave: 4 global_load_lds (B) + 2 A-frag loads = 6 VMEM.
// 3 chunks in flight -> s_waitcnt vmcnt(12) retires chunk s (in-order retire;
// robust to extra NEWER compiler-inserted VMEM). Buffer safety: STAGE(s+3)
// (issued after barrier(s)) overwrites buf[(s-1)&3], whose reads all
// completed before barrier(s). Rolling A-pipe ap[4][2] statically indexed
// via full unroll. b in [0,512): nt = b&31, mi = (b>>5)*4 + wave.
// ---------------------------------------------------------------------------
template<int KI, int FINAL>
__device__ __forceinline__ void layer_body(
    int b, const bf16x8* __restrict__ Ap, const bf16x8* __restrict__ Wp,
    const float* __restrict__ coeff, const float* __restrict__ bias,
    __bf16* __restrict__ ApN, float* __restrict__ fout, bf16x8* bs)
{
    constexpr int NS = KI / 2;                 // K-chunks of 2 ki
    const int lane = threadIdx.x & 63, w = threadIdx.x >> 6;
    const int q = lane >> 4, r = lane & 15;
    const int nt = b & 31, by = b >> 5;
    const int o0 = nt * 16;
    const int mi = by * 4 + w;                 // this wave's m-tile

    const bf16x8* aB = Ap + (size_t)mi * KI * 64 + lane;
    const int e0 = w * 2;                      // this wave stages experts e0, e0+1

    f32x4 acc[E_];
#pragma unroll
    for (int e = 0; e < E_; e++) acc[e] = (f32x4){0.f, 0.f, 0.f, 0.f};

    // bs index: [buf(4)][kk(2)][e(8)][lane(64)]
#define BSI(buf_, kk_, e_) (&bs[(((size_t)(buf_) * 2 + (kk_)) * E_ + (e_)) * 64])
#define STAGE(s_, buf_)                                                        \
    {                                                                          \
        _Pragma("unroll")                                                      \
        for (int kk = 0; kk < 2; ++kk) {                                       \
            _Pragma("unroll")                                                  \
            for (int t = 0; t < 2; ++t) {                                      \
                const int e = e0 + t;                                          \
                const bf16x8* g = Wp +                                         \
                    ((size_t)e * 32 * KI + (size_t)nt * KI + ((s_) * 2 + kk)) * 64 + lane; \
                async_ld16((const void*)g, (void*)BSI(buf_, kk, e));           \
            }                                                                  \
        }                                                                      \
    }

    bf16x8 ap[4][2];                           // rolling A pipeline
    STAGE(0, 0); ap[0][0] = aB[0];      ap[0][1] = aB[64];
    if (NS > 1) { STAGE(1, 1); ap[1][0] = aB[2 * 64]; ap[1][1] = aB[3 * 64]; }
    if (NS > 2) { STAGE(2, 2); ap[2][0] = aB[4 * 64]; ap[2][1] = aB[5 * 64]; }

#pragma unroll
    for (int s = 0; s < NS; ++s) {
        // retire chunk s (6 VMEM per in-flight chunk, in-order retire)
        if (s + 2 < NS)      asm volatile("s_waitcnt vmcnt(12)" ::: "memory");
        else if (s + 1 < NS) asm volatile("s_waitcnt vmcnt(6)"  ::: "memory");
        else                 asm volatile("s_waitcnt vmcnt(0)"  ::: "memory");
        __builtin_amdgcn_s_barrier();          // all waves' chunk-s stages done
        __builtin_amdgcn_sched_barrier(0);

        bf16x8 bfr[2][E_];
#pragma unroll
        for (int kk = 0; kk < 2; ++kk)
#pragma unroll
            for (int e = 0; e < E_; e++) bfr[kk][e] = *(BSI(s & 3, kk, e) + lane);

        if (s + 3 < NS) {                      // issue next stage (6 VMEM)
            STAGE(s + 3, (s + 3) & 3);
            ap[(s + 3) & 3][0] = aB[(size_t)(2 * s + 6) * 64];
            ap[(s + 3) & 3][1] = aB[(size_t)(2 * s + 7) * 64];
        }

#pragma unroll
        for (int kk = 0; kk < 2; ++kk) {
            const bf16x8 af = ap[s & 3][kk];
#pragma unroll
            for (int e = 0; e < E_; e++)
                acc[e] = __builtin_amdgcn_mfma_f32_16x16x32_bf16(af, bfr[kk][e], acc[e], 0, 0, 0);
        }
    }
#undef STAGE
#undef BSI

    // epilogue: s = sum_e coeff[row,e]*(acc[e]+bias[e,o])
    float be[E_];
#pragma unroll
    for (int e = 0; e < E_; e++) be[e] = bias[(size_t)e * 512 + o0 + r];

    // D layout: col(o) = lane&15, row(m) = q*4 + v  [m89-verified]
#pragma unroll
    for (int v = 0; v < 4; v++) {
        const int row = mi * 16 + q * 4 + v;
        const float* cr = coeff + (size_t)row * E_;
        const f32x4 clo = *(const f32x4*)cr, chi = *(const f32x4*)(cr + 4);
        float sv = 0.f;
#pragma unroll
        for (int e = 0; e < 4; e++) sv += clo[e] * (acc[e][v] + be[e]);
#pragma unroll
        for (int e = 0; e < 4; e++) sv += chi[e] * (acc[4 + e][v] + be[4 + e]);
        if (FINAL) {
            fout[(size_t)row * OUT_SZ + o0 + r] = sv;
        } else {
            const float hh = elu_f(sv);
            const int k  = LAT + o0 + r;           // 64..575
            const int ki2 = k >> 5, kq2 = (k & 31) >> 3, jb2 = k & 7;
            ApN[(((size_t)mi * KI12 + ki2) * 64 + kq2 * 16 + (q * 4 + v)) * 8 + jb2] =
                to_bf16(hh);
        }
    }
}

// ---------------------------------------------------------------------------
// D1: gate(64) + zcpack(160) + wpack0 halves(320) = 544 blocks.
// ---------------------------------------------------------------------------
#define D1_GATE 64
#define D1_ZC   (D1_GATE + 160)              // 224
#define D1_ALL  (D1_ZC + 8 * KI0 * 4)        // 544

__global__ __launch_bounds__(256, 4) void prep_kernel(
    const float* __restrict__ z, const float* __restrict__ c,
    const float* __restrict__ w0,
    const float* __restrict__ gw1, const float* __restrict__ gb1,
    const float* __restrict__ gw2, const float* __restrict__ gb2,
    const float* __restrict__ gw3, const float* __restrict__ gb3,
    bf16x8* __restrict__ Ap0, bf16x8* __restrict__ Ap1, bf16x8* __restrict__ Ap2,
    bf16x8* __restrict__ Wp0,
    float* __restrict__ coeff)
{
    __shared__ __align__(16) uint8_t smem[SMEM_PREP];
    const int bx = blockIdx.x;
    if (bx < D1_GATE) {
        do_gate(bx, z, c, gw1, gb1, gw2, gb2, gw3, gb3, coeff, (float*)smem);
    } else if (bx < D1_ZC) {
        do_zcpack(bx - D1_GATE, z, c, Ap0, Ap1, Ap2);
    } else {
        do_wpackh(bx - D1_ZC, w0, Wp0, KI0, (float*)smem);
    }
}

// ---------------------------------------------------------------------------
// D2/D3/D4: layer (512 blocks, 64 KB LDS depth-3 pipeline) + independent
// next-layer weight pack (576 half units for w1/w2; 0 for final).
// Dependency enforced by dispatch boundaries only (no intra-dispatch sync).
// ---------------------------------------------------------------------------
template<int KI, int FINAL>
__global__ __launch_bounds__(256, 2) void layer_wpack_kernel(
    const bf16x8* __restrict__ Ap, const bf16x8* __restrict__ Wp,
    const float* __restrict__ coeff, const float* __restrict__ bias,
    __bf16* __restrict__ ApN, float* __restrict__ fout,
    const float* __restrict__ wsrc, bf16x8* __restrict__ WpN)
{
    __shared__ __align__(16) uint8_t smem[4 * 2 * E_ * 64 * 16];   // 64 KB
    const int b = blockIdx.x;
    if (b < 512) {
        layer_body<KI, FINAL>(b, Ap, Wp, coeff, bias, ApN, fout, (bf16x8*)smem);
    } else {
        do_wpackh(b - 512, wsrc, WpN, KI12, (float*)smem);
    }
}

// ---------------------------------------------------------------------------
static inline size_t align256(size_t x) { return (x + 255) & ~(size_t)255; }

extern "C" void kernel_launch(void* const* d_in, const int* in_sizes, int n_in,
                              void* d_out, int out_size, void* d_ws, size_t ws_size,
                              hipStream_t stream)
{
    const float* z   = (const float*)d_in[0];
    const float* c   = (const float*)d_in[1];
    const float* w0  = (const float*)d_in[2];
    const float* b0  = (const float*)d_in[3];
    const float* w1  = (const float*)d_in[4];
    const float* b1  = (const float*)d_in[5];
    const float* w2  = (const float*)d_in[6];
    const float* b2  = (const float*)d_in[7];
    const float* gw1 = (const float*)d_in[8];
    const float* gb1 = (const float*)d_in[9];
    const float* gw2 = (const float*)d_in[10];
    const float* gb2 = (const float*)d_in[11];
    const float* gw3 = (const float*)d_in[12];
    const float* gb3 = (const float*)d_in[13];
    float* out = (float*)d_out;

    uint8_t* p = (uint8_t*)d_ws;
    bf16x8* Wp0 = (bf16x8*)p; p += align256((size_t)NTOT * IN_SZ * 2);
    bf16x8* Wp1 = (bf16x8*)p; p += align256((size_t)NTOT * INTER * 2);
    bf16x8* Wp2 = (bf16x8*)p; p += align256((size_t)NTOT * INTER * 2);
    bf16x8* Ap0 = (bf16x8*)p; p += align256((size_t)B_ * IN_SZ * 2);
    bf16x8* Ap1 = (bf16x8*)p; p += align256((size_t)B_ * INTER * 2);
    bf16x8* Ap2 = (bf16x8*)p; p += align256((size_t)B_ * INTER * 2);
    float* coeff = (float*)p; p += align256((size_t)B_ * E_ * 4);

    // D1: gate + zc-pack + w0-pack (544 blocks)
    prep_kernel<<<D1_ALL, 256, 0, stream>>>(
        z, c, w0, gw1, gb1, gw2, gb2, gw3, gb3,
        Ap0, Ap1, Ap2, Wp0, coeff);

    // D2: layer0 (depth-3 pipeline) + w1-pack overlapped
    layer_wpack_kernel<KI0, 0><<<512 + 8 * KI12 * 4, 256, 0, stream>>>(
        Ap0, Wp0, coeff, b0, (__bf16*)Ap1, nullptr, w1, Wp1);

    // D3: layer1 + w2-pack overlapped
    layer_wpack_kernel<KI12, 0><<<512 + 8 * KI12 * 4, 256, 0, stream>>>(
        Ap1, Wp1, coeff, b1, (__bf16*)Ap2, nullptr, w2, Wp2);

    // D4: layer2
    layer_wpack_kernel<KI12, 1><<<512, 256, 0, stream>>>(
        Ap2, Wp2, coeff, b2, nullptr, out, nullptr, nullptr);
}